// Round 1
// baseline (1567.587 us; speedup 1.0000x reference)
//
#include <hip/hip_runtime.h>
#include <math.h>

// Shapes (fixed by the problem)
constexpr int Bn = 4, Tn = 1024, Dn = 1024, Hn = 8, DH = 128;
constexpr float EPSF = 1e-10f;
constexpr float LN_EPSF = 1e-5f;
constexpr float NEGF = -1e30f;

// ---------------------------------------------------------------------------
// K0: x = where(pad, 0, inputs)
// ---------------------------------------------------------------------------
__global__ __launch_bounds__(256) void mask_x_kernel(const float4* __restrict__ in,
                                                     const int* __restrict__ lengths,
                                                     float4* __restrict__ x) {
    const int i = blockIdx.x * 256 + threadIdx.x;   // 1M float4s
    const int row = i >> 8;                          // 256 float4 per row (D=1024)
    const int t = row & 1023;
    const int b = row >> 10;
    float4 v = in[i];
    if (t >= lengths[b]) { v.x = 0.f; v.y = 0.f; v.z = 0.f; v.w = 0.f; }
    x[i] = v;
}

// ---------------------------------------------------------------------------
// K1: projections  h = x @ W^T, reshaped to (B,H,T,dh). 5 weights in one grid.z
// C[m,n] = sum_k X[m,k] * W[n,k]   (both row-major, dot along contiguous K)
// ---------------------------------------------------------------------------
struct ProjArgs {
    const float* W[5];
    float* O[5];
};

__global__ __launch_bounds__(256) void proj_gemm(const float* __restrict__ X, ProjArgs args) {
    constexpr int BK = 32;
    const float* __restrict__ W = args.W[blockIdx.z];
    float* __restrict__ O = args.O[blockIdx.z];
    const int m0 = blockIdx.y << 6;
    const int n0 = blockIdx.x << 6;
    __shared__ float As[64][BK + 1];
    __shared__ float Bs[64][BK + 1];
    const int tid = threadIdx.x;
    const int tx = tid & 15, ty = tid >> 4;
    float acc[4][4] = {};
    for (int k0 = 0; k0 < Dn; k0 += BK) {
#pragma unroll
        for (int l = 0; l < 2; ++l) {
            const int f = tid + (l << 8);
            const int r = f >> 3, c = (f & 7) << 2;
            const float4 av = *reinterpret_cast<const float4*>(X + (size_t)(m0 + r) * Dn + k0 + c);
            const float4 bv = *reinterpret_cast<const float4*>(W + (size_t)(n0 + r) * Dn + k0 + c);
            As[r][c] = av.x; As[r][c + 1] = av.y; As[r][c + 2] = av.z; As[r][c + 3] = av.w;
            Bs[r][c] = bv.x; Bs[r][c + 1] = bv.y; Bs[r][c + 2] = bv.z; Bs[r][c + 3] = bv.w;
        }
        __syncthreads();
#pragma unroll
        for (int kk = 0; kk < BK; ++kk) {
            float a[4], b[4];
#pragma unroll
            for (int i = 0; i < 4; ++i) a[i] = As[ty * 4 + i][kk];
#pragma unroll
            for (int j = 0; j < 4; ++j) b[j] = Bs[tx * 4 + j][kk];
#pragma unroll
            for (int i = 0; i < 4; ++i)
#pragma unroll
                for (int j = 0; j < 4; ++j)
                    acc[i][j] = fmaf(a[i], b[j], acc[i][j]);
        }
        __syncthreads();
    }
#pragma unroll
    for (int i = 0; i < 4; ++i) {
        const int m = m0 + ty * 4 + i;
        const int b = m >> 10, t = m & 1023;
#pragma unroll
        for (int j = 0; j < 4; ++j) {
            const int n = n0 + tx * 4 + j;
            const int h = n >> 7, d = n & 127;
            O[((size_t)(b * Hn + h) * Tn + t) * DH + d] = acc[i][j];
        }
    }
}

// ---------------------------------------------------------------------------
// K2: scores = (q @ k^T) / 32 per (b,h), written RAW into the attn output slot
// ---------------------------------------------------------------------------
__global__ __launch_bounds__(256) void scores_gemm(const float* __restrict__ Q,
                                                   const float* __restrict__ Kp,
                                                   float* __restrict__ S) {
    constexpr int BK = 32;
    const int z = blockIdx.z;
    const float* __restrict__ q = Q + (size_t)z * Tn * DH;
    const float* __restrict__ k = Kp + (size_t)z * Tn * DH;
    const int m0 = blockIdx.y << 6;
    const int n0 = blockIdx.x << 6;
    __shared__ float As[64][BK + 1];
    __shared__ float Bs[64][BK + 1];
    const int tid = threadIdx.x;
    const int tx = tid & 15, ty = tid >> 4;
    float acc[4][4] = {};
    for (int k0 = 0; k0 < DH; k0 += BK) {
#pragma unroll
        for (int l = 0; l < 2; ++l) {
            const int f = tid + (l << 8);
            const int r = f >> 3, c = (f & 7) << 2;
            const float4 av = *reinterpret_cast<const float4*>(q + (size_t)(m0 + r) * DH + k0 + c);
            const float4 bv = *reinterpret_cast<const float4*>(k + (size_t)(n0 + r) * DH + k0 + c);
            As[r][c] = av.x; As[r][c + 1] = av.y; As[r][c + 2] = av.z; As[r][c + 3] = av.w;
            Bs[r][c] = bv.x; Bs[r][c + 1] = bv.y; Bs[r][c + 2] = bv.z; Bs[r][c + 3] = bv.w;
        }
        __syncthreads();
#pragma unroll
        for (int kk = 0; kk < BK; ++kk) {
            float a[4], b[4];
#pragma unroll
            for (int i = 0; i < 4; ++i) a[i] = As[ty * 4 + i][kk];
#pragma unroll
            for (int j = 0; j < 4; ++j) b[j] = Bs[tx * 4 + j][kk];
#pragma unroll
            for (int i = 0; i < 4; ++i)
#pragma unroll
                for (int j = 0; j < 4; ++j)
                    acc[i][j] = fmaf(a[i], b[j], acc[i][j]);
        }
        __syncthreads();
    }
    const float scale = 1.f / 32.f;  // 1/sqrt(D=1024)
#pragma unroll
    for (int i = 0; i < 4; ++i) {
        const int m = m0 + ty * 4 + i;
#pragma unroll
        for (int j = 0; j < 4; ++j) {
            const int n = n0 + tx * 4 + j;
            S[((size_t)z * Tn + m) * Tn + n] = acc[i][j] * scale;
        }
    }
}

// ---------------------------------------------------------------------------
// K3: edge = eq @ ek^T; edges_prob = sigmoid(edge); gate via binary-concrete;
//     masked scores rewritten in place in the attn slot.
// ---------------------------------------------------------------------------
__global__ __launch_bounds__(256) void edge_gemm(const float* __restrict__ EQ,
                                                 const float* __restrict__ EK,
                                                 const float* __restrict__ U,
                                                 const int* __restrict__ lengths,
                                                 float* __restrict__ S,
                                                 float* __restrict__ EP) {
    constexpr int BK = 32;
    const int z = blockIdx.z;
    const int len = lengths[z >> 3];
    const float* __restrict__ q = EQ + (size_t)z * Tn * DH;
    const float* __restrict__ k = EK + (size_t)z * Tn * DH;
    const int m0 = blockIdx.y << 6;
    const int n0 = blockIdx.x << 6;
    __shared__ float As[64][BK + 1];
    __shared__ float Bs[64][BK + 1];
    const int tid = threadIdx.x;
    const int tx = tid & 15, ty = tid >> 4;
    float acc[4][4] = {};
    for (int k0 = 0; k0 < DH; k0 += BK) {
#pragma unroll
        for (int l = 0; l < 2; ++l) {
            const int f = tid + (l << 8);
            const int r = f >> 3, c = (f & 7) << 2;
            const float4 av = *reinterpret_cast<const float4*>(q + (size_t)(m0 + r) * DH + k0 + c);
            const float4 bv = *reinterpret_cast<const float4*>(k + (size_t)(n0 + r) * DH + k0 + c);
            As[r][c] = av.x; As[r][c + 1] = av.y; As[r][c + 2] = av.z; As[r][c + 3] = av.w;
            Bs[r][c] = bv.x; Bs[r][c + 1] = bv.y; Bs[r][c + 2] = bv.z; Bs[r][c + 3] = bv.w;
        }
        __syncthreads();
#pragma unroll
        for (int kk = 0; kk < BK; ++kk) {
            float a[4], b[4];
#pragma unroll
            for (int i = 0; i < 4; ++i) a[i] = As[ty * 4 + i][kk];
#pragma unroll
            for (int j = 0; j < 4; ++j) b[j] = Bs[tx * 4 + j][kk];
#pragma unroll
            for (int i = 0; i < 4; ++i)
#pragma unroll
                for (int j = 0; j < 4; ++j)
                    acc[i][j] = fmaf(a[i], b[j], acc[i][j]);
        }
        __syncthreads();
    }
#pragma unroll
    for (int i = 0; i < 4; ++i) {
        const int m = m0 + ty * 4 + i;
#pragma unroll
        for (int j = 0; j < 4; ++j) {
            const int n = n0 + tx * 4 + j;
            const size_t idx = ((size_t)z * Tn + m) * Tn + n;
            const float e = acc[i][j];
            const float p = 1.f / (1.f + expf(-e));
            EP[idx] = p;
            const float u = U[idx];
            const float zz = logf(p + EPSF) - logf(1.f - p + EPSF) +
                             logf(u + EPSF) - logf(1.f - u + EPSF);
            const bool valid = (zz > 0.f) && (n < len);
            const float sc = S[idx];
            S[idx] = valid ? sc : NEGF;
        }
    }
}

// ---------------------------------------------------------------------------
// K4: row softmax, in place on the attn slot. Zero fully-masked rows.
// ---------------------------------------------------------------------------
__global__ __launch_bounds__(256) void softmax_rows(float* __restrict__ attn) {
    __shared__ float redm[4];
    __shared__ float reds[4];
    const size_t base = (size_t)blockIdx.x * Tn;
    float4* rowp = reinterpret_cast<float4*>(attn + base);
    float4 s = rowp[threadIdx.x];
    float m = fmaxf(fmaxf(s.x, s.y), fmaxf(s.z, s.w));
#pragma unroll
    for (int off = 32; off >= 1; off >>= 1) m = fmaxf(m, __shfl_xor(m, off));
    if ((threadIdx.x & 63) == 0) redm[threadIdx.x >> 6] = m;
    __syncthreads();
    m = fmaxf(fmaxf(redm[0], redm[1]), fmaxf(redm[2], redm[3]));
    const bool any = m > -5e29f;
    float4 e;
    e.x = expf(s.x - m);
    e.y = expf(s.y - m);
    e.z = expf(s.z - m);
    e.w = expf(s.w - m);
    float sum = e.x + e.y + e.z + e.w;
#pragma unroll
    for (int off = 32; off >= 1; off >>= 1) sum += __shfl_xor(sum, off);
    if ((threadIdx.x & 63) == 0) reds[threadIdx.x >> 6] = sum;
    __syncthreads();
    sum = reds[0] + reds[1] + reds[2] + reds[3];
    const float inv = any ? 1.f / sum : 0.f;
    e.x *= inv; e.y *= inv; e.z *= inv; e.w *= inv;
    rowp[threadIdx.x] = e;
}

// ---------------------------------------------------------------------------
// K5: ctx = relu(attn @ v), written to (B,T,D) layout
// ---------------------------------------------------------------------------
__global__ __launch_bounds__(256) void ctx_gemm(const float* __restrict__ A,
                                                const float* __restrict__ V,
                                                float* __restrict__ C) {
    constexpr int BK = 32;
    const int z = blockIdx.z;
    const int bb = z >> 3, h = z & 7;
    const float* __restrict__ a = A + (size_t)z * Tn * Tn;
    const float* __restrict__ v = V + (size_t)z * Tn * DH;
    const int m0 = blockIdx.y << 6;
    const int n0 = blockIdx.x << 6;
    __shared__ float As[64][BK + 1];
    __shared__ float Bs[BK][64];
    const int tid = threadIdx.x;
    const int tx = tid & 15, ty = tid >> 4;
    float acc[4][4] = {};
    for (int k0 = 0; k0 < Tn; k0 += BK) {
#pragma unroll
        for (int l = 0; l < 2; ++l) {
            const int f = tid + (l << 8);
            {
                const int r = f >> 3, c = (f & 7) << 2;
                const float4 av = *reinterpret_cast<const float4*>(a + (size_t)(m0 + r) * Tn + k0 + c);
                As[r][c] = av.x; As[r][c + 1] = av.y; As[r][c + 2] = av.z; As[r][c + 3] = av.w;
            }
            {
                const int r = f >> 4, c = (f & 15) << 2;
                const float4 bv = *reinterpret_cast<const float4*>(v + (size_t)(k0 + r) * DH + n0 + c);
                Bs[r][c] = bv.x; Bs[r][c + 1] = bv.y; Bs[r][c + 2] = bv.z; Bs[r][c + 3] = bv.w;
            }
        }
        __syncthreads();
#pragma unroll
        for (int kk = 0; kk < BK; ++kk) {
            float av[4], bv[4];
#pragma unroll
            for (int i = 0; i < 4; ++i) av[i] = As[ty * 4 + i][kk];
#pragma unroll
            for (int j = 0; j < 4; ++j) bv[j] = Bs[kk][tx * 4 + j];
#pragma unroll
            for (int i = 0; i < 4; ++i)
#pragma unroll
                for (int j = 0; j < 4; ++j)
                    acc[i][j] = fmaf(av[i], bv[j], acc[i][j]);
        }
        __syncthreads();
    }
#pragma unroll
    for (int i = 0; i < 4; ++i) {
        const int m = m0 + ty * 4 + i;
#pragma unroll
        for (int j = 0; j < 4; ++j) {
            const int n = n0 + tx * 4 + j;
            C[((size_t)(bb * Tn + m)) * Dn + h * DH + n] = fmaxf(acc[i][j], 0.f);
        }
    }
}

// ---------------------------------------------------------------------------
// K6/K8: layernorm. FINAL=true also zeroes padded rows and has no residual.
// ---------------------------------------------------------------------------
template <bool FINAL>
__global__ __launch_bounds__(256) void ln_kernel(const float* __restrict__ a,
                                                 const float* __restrict__ res,
                                                 const float* __restrict__ g,
                                                 const float* __restrict__ bb,
                                                 const int* __restrict__ lengths,
                                                 float* __restrict__ o) {
    __shared__ float red1[4];
    __shared__ float red2[4];
    const int row = blockIdx.x;
    const size_t base = (size_t)row * Dn;
    const int tid = threadIdx.x;
    float4 v = reinterpret_cast<const float4*>(a + base)[tid];
    if (!FINAL) {
        const float4 r = reinterpret_cast<const float4*>(res + base)[tid];
        v.x += r.x; v.y += r.y; v.z += r.z; v.w += r.w;
    }
    float s = v.x + v.y + v.z + v.w;
#pragma unroll
    for (int off = 32; off >= 1; off >>= 1) s += __shfl_xor(s, off);
    if ((tid & 63) == 0) red1[tid >> 6] = s;
    __syncthreads();
    const float mu = (red1[0] + red1[1] + red1[2] + red1[3]) * (1.f / Dn);
    const float d0 = v.x - mu, d1 = v.y - mu, d2 = v.z - mu, d3 = v.w - mu;
    float sq = d0 * d0 + d1 * d1 + d2 * d2 + d3 * d3;
#pragma unroll
    for (int off = 32; off >= 1; off >>= 1) sq += __shfl_xor(sq, off);
    if ((tid & 63) == 0) red2[tid >> 6] = sq;
    __syncthreads();
    const float var = (red2[0] + red2[1] + red2[2] + red2[3]) * (1.f / Dn);
    const float rstd = rsqrtf(var + LN_EPSF);
    const float4 gv = reinterpret_cast<const float4*>(g)[tid];
    const float4 bv = reinterpret_cast<const float4*>(bb)[tid];
    float4 ov;
    ov.x = d0 * rstd * gv.x + bv.x;
    ov.y = d1 * rstd * gv.y + bv.y;
    ov.z = d2 * rstd * gv.z + bv.z;
    ov.w = d3 * rstd * gv.w + bv.w;
    if (FINAL) {
        const int t = row & 1023, b = row >> 10;
        if (t >= lengths[b]) { ov.x = 0.f; ov.y = 0.f; ov.z = 0.f; ov.w = 0.f; }
    }
    reinterpret_cast<float4*>(o + base)[tid] = ov;
}

// ---------------------------------------------------------------------------
// K7: h2 = relu(h1 @ Wfc^T + bfc) + h1
// ---------------------------------------------------------------------------
__global__ __launch_bounds__(256) void fc_gemm(const float* __restrict__ X,
                                               const float* __restrict__ W,
                                               const float* __restrict__ bias,
                                               float* __restrict__ O) {
    constexpr int BK = 32;
    const int m0 = blockIdx.y << 6;
    const int n0 = blockIdx.x << 6;
    __shared__ float As[64][BK + 1];
    __shared__ float Bs[64][BK + 1];
    const int tid = threadIdx.x;
    const int tx = tid & 15, ty = tid >> 4;
    float acc[4][4] = {};
    for (int k0 = 0; k0 < Dn; k0 += BK) {
#pragma unroll
        for (int l = 0; l < 2; ++l) {
            const int f = tid + (l << 8);
            const int r = f >> 3, c = (f & 7) << 2;
            const float4 av = *reinterpret_cast<const float4*>(X + (size_t)(m0 + r) * Dn + k0 + c);
            const float4 bv = *reinterpret_cast<const float4*>(W + (size_t)(n0 + r) * Dn + k0 + c);
            As[r][c] = av.x; As[r][c + 1] = av.y; As[r][c + 2] = av.z; As[r][c + 3] = av.w;
            Bs[r][c] = bv.x; Bs[r][c + 1] = bv.y; Bs[r][c + 2] = bv.z; Bs[r][c + 3] = bv.w;
        }
        __syncthreads();
#pragma unroll
        for (int kk = 0; kk < BK; ++kk) {
            float a[4], b[4];
#pragma unroll
            for (int i = 0; i < 4; ++i) a[i] = As[ty * 4 + i][kk];
#pragma unroll
            for (int j = 0; j < 4; ++j) b[j] = Bs[tx * 4 + j][kk];
#pragma unroll
            for (int i = 0; i < 4; ++i)
#pragma unroll
                for (int j = 0; j < 4; ++j)
                    acc[i][j] = fmaf(a[i], b[j], acc[i][j]);
        }
        __syncthreads();
    }
#pragma unroll
    for (int i = 0; i < 4; ++i) {
        const int m = m0 + ty * 4 + i;
#pragma unroll
        for (int j = 0; j < 4; ++j) {
            const int n = n0 + tx * 4 + j;
            const float h1v = X[(size_t)m * Dn + n];
            O[(size_t)m * Dn + n] = fmaxf(acc[i][j] + bias[n], 0.f) + h1v;
        }
    }
}

// ---------------------------------------------------------------------------
extern "C" void kernel_launch(void* const* d_in, const int* in_sizes, int n_in,
                              void* d_out, int out_size, void* d_ws, size_t ws_size,
                              hipStream_t stream) {
    const float* inputs = (const float*)d_in[0];
    const int* lengths = (const int*)d_in[1];
    const float* noise = (const float*)d_in[2];
    const float* Wq = (const float*)d_in[3];
    const float* Wk = (const float*)d_in[4];
    const float* Wv = (const float*)d_in[5];
    const float* Weq = (const float*)d_in[6];
    const float* Wek = (const float*)d_in[7];
    const float* Wfc = (const float*)d_in[8];
    const float* bfc = (const float*)d_in[9];
    const float* ln1_g = (const float*)d_in[10];
    const float* ln1_b = (const float*)d_in[11];
    const float* ln2_g = (const float*)d_in[12];
    const float* ln2_b = (const float*)d_in[13];

    float* out = (float*)d_out;                       // (B,T,D)   4M floats
    float* attn = out + (size_t)Bn * Tn * Dn;         // (B,H,T,T) 32M floats
    float* ep = attn + (size_t)Bn * Hn * Tn * Tn;     // (B,H,T,T) 32M floats

    constexpr size_t SLOT = (size_t)Bn * Tn * Dn;     // 4M floats
    float* ws = (float*)d_ws;
    float* x = ws;               // [0,4M)
    float* q = ws + SLOT;        // [4M,8M)
    float* k = ws + 2 * SLOT;    // [8M,12M)
    float* v = ws + 3 * SLOT;    // [12M,16M)
    float* eq = ws + 4 * SLOT;   // [16M,20M)
    float* ek = ws + 5 * SLOT;   // [20M,24M)
    float* ctx = eq;             // reuse after edge_gemm
    float* h1 = ek;              // reuse after edge_gemm
    float* h2 = q;               // reuse after scores_gemm

    // K0: masked input
    mask_x_kernel<<<dim3((Bn * Tn * Dn) / 4 / 256), 256, 0, stream>>>(
        (const float4*)inputs, lengths, (float4*)x);

    // K1: 5 projections
    ProjArgs pa;
    pa.W[0] = Wq; pa.W[1] = Wk; pa.W[2] = Wv; pa.W[3] = Weq; pa.W[4] = Wek;
    pa.O[0] = q; pa.O[1] = k; pa.O[2] = v; pa.O[3] = eq; pa.O[4] = ek;
    proj_gemm<<<dim3(Dn / 64, (Bn * Tn) / 64, 5), 256, 0, stream>>>(x, pa);

    // K2: raw scores into attn slot
    scores_gemm<<<dim3(Tn / 64, Tn / 64, Bn * Hn), 256, 0, stream>>>(q, k, attn);

    // K3: edge GEMM + gate + mask (in place on attn slot), writes edges_prob
    edge_gemm<<<dim3(Tn / 64, Tn / 64, Bn * Hn), 256, 0, stream>>>(eq, ek, noise, lengths, attn, ep);

    // K4: softmax in place
    softmax_rows<<<dim3(Bn * Hn * Tn), 256, 0, stream>>>(attn);

    // K5: ctx = relu(attn @ v) -> (B,T,D)
    ctx_gemm<<<dim3(DH / 64, Tn / 64, Bn * Hn), 256, 0, stream>>>(attn, v, ctx);

    // K6: h1 = LN(ctx + x)
    ln_kernel<false><<<dim3(Bn * Tn), 256, 0, stream>>>(ctx, x, ln1_g, ln1_b, lengths, h1);

    // K7: h2 = relu(h1 @ Wfc^T + bfc) + h1
    fc_gemm<<<dim3(Dn / 64, (Bn * Tn) / 64, 1), 256, 0, stream>>>(h1, Wfc, bfc, h2);

    // K8: out = LN(h2), zero padded rows
    ln_kernel<true><<<dim3(Bn * Tn), 256, 0, stream>>>(h2, nullptr, ln2_g, ln2_b, lengths, out);
}

// Round 4
// 533.460 us; speedup vs baseline: 2.9385x; 2.9385x over previous
//
#include <hip/hip_runtime.h>
#include <math.h>

// Shapes (fixed by the problem)
constexpr int Bn = 4, Tn = 1024, Dn = 1024, Hn = 8, DH = 128;
constexpr float EPSF = 1e-10f;
constexpr float LN_EPSF = 1e-5f;
constexpr float NEGF = -1e30f;

typedef __attribute__((ext_vector_type(8))) short bf16x8;   // 8 bf16 in 4 VGPRs
typedef __attribute__((ext_vector_type(4))) float f32x4;
typedef __attribute__((ext_vector_type(4))) unsigned uint4v;

#define MFMA16(a, b, c) __builtin_amdgcn_mfma_f32_16x16x32_bf16(a, b, c, 0, 0, 0)

// f32 -> bf16 round-to-nearest-even
__device__ __forceinline__ short f2bf(float f) {
    unsigned u = __builtin_bit_cast(unsigned, f);
    u += 0x7fffu + ((u >> 16) & 1u);
    return (short)(u >> 16);
}
__device__ __forceinline__ float bf2f(short h) {
    return __builtin_bit_cast(float, ((unsigned)(unsigned short)h) << 16);
}
__device__ __forceinline__ unsigned pack2(float a, float b) {
    return ((unsigned)(unsigned short)f2bf(a)) | (((unsigned)(unsigned short)f2bf(b)) << 16);
}

// async global->LDS, 16B per lane. lds ptr must be wave-uniform.
__device__ __forceinline__ void gload16(const void* g, void* l) {
    __builtin_amdgcn_global_load_lds((__attribute__((address_space(1))) void*)g,
                                     (__attribute__((address_space(3))) void*)l,
                                     16, 0, 0);
}

// Stage a 128x32 bf16 tile from row-major global (ld elems/row).
// LDS layout: [kb:4][r:128][8 bf16]; chunk c = kb*128 + r. 8 gload16 total.
template <int NW>
__device__ __forceinline__ void stage_b(const short* g, int ld, short* lds, int lane, int wid) {
#pragma unroll
    for (int s = 0; s < 8 / NW; ++s) {
        const int ii = wid * (8 / NW) + s;
        const int c = ii * 64 + lane;
        const int kb = c >> 7, r = c & 127;
        gload16(g + (size_t)r * ld + kb * 8, lds + ii * 512);
    }
}

// Stage a 128x32 f32 tile. LDS layout: [kb:4][half:2][r:128][4 f32]. 16 gload16.
template <int NW>
__device__ __forceinline__ void stage_f(const float* g, int ld, float* lds, int lane, int wid) {
#pragma unroll
    for (int s = 0; s < 16 / NW; ++s) {
        const int ii = wid * (16 / NW) + s;
        const int c = ii * 64 + lane;
        const int kb = c >> 8, half = (c >> 7) & 1, r = c & 127;
        gload16(g + (size_t)r * ld + kb * 8 + half * 4, lds + ii * 256);
    }
}

__device__ __forceinline__ bf16x8 fragb(const short* lds, int kbl, int r) {
    return *reinterpret_cast<const bf16x8*>(lds + kbl * 1024 + r * 8);
}

// fp32-staged fragment -> bf16x8 with RNE rounding
__device__ __forceinline__ bf16x8 fragf(const float* lds, int kbl, int r) {
    const f32x4 lo = *reinterpret_cast<const f32x4*>(lds + kbl * 1024 + r * 4);
    const f32x4 hi = *reinterpret_cast<const f32x4*>(lds + kbl * 1024 + 512 + r * 4);
    uint4v p;
    p[0] = pack2(lo[0], lo[1]);
    p[1] = pack2(lo[2], lo[3]);
    p[2] = pack2(hi[0], hi[1]);
    p[3] = pack2(hi[2], hi[3]);
    return __builtin_bit_cast(bf16x8, p);
}

// ---------------------------------------------------------------------------
// weights -> bf16 hi (all 6) + lo (Weq,Wek,Wfc only: mats 3,4,5)
// ---------------------------------------------------------------------------
struct CvtP { const float* src[6]; short* hi; short* lo; };

__global__ __launch_bounds__(256) void cvt_w(CvtP p) {
    const int i = blockIdx.x * 256 + threadIdx.x;       // 786432 threads x 8 elems
    const int mat = i >> 17;
    const int off = (i & 131071) * 8;
    const float* s = p.src[mat] + off;
    const float4 a = *reinterpret_cast<const float4*>(s);
    const float4 b = *reinterpret_cast<const float4*>(s + 4);
    const float va[8] = {a.x, a.y, a.z, a.w, b.x, b.y, b.z, b.w};
    bf16x8 h, l;
#pragma unroll
    for (int j = 0; j < 8; ++j) {
        h[j] = f2bf(va[j]);
        l[j] = f2bf(va[j] - bf2f(h[j]));
    }
    *reinterpret_cast<bf16x8*>(p.hi + (size_t)mat * 1048576 + off) = h;
    if (mat >= 3)
        *reinterpret_cast<bf16x8*>(p.lo + (size_t)(mat - 3) * 1048576 + off) = l;
}

// ---------------------------------------------------------------------------
// x = where(pad,0,inputs) -> split bf16 (hi, lo)
// ---------------------------------------------------------------------------
__global__ __launch_bounds__(256) void mask_x(const float4* __restrict__ in,
                                              const int* __restrict__ lengths,
                                              short* __restrict__ xhi,
                                              short* __restrict__ xlo) {
    const int i = blockIdx.x * 256 + threadIdx.x;       // 1M float4
    const int row = i >> 8;
    const int t = row & 1023, b = row >> 10;
    float4 v = in[i];
    if (t >= lengths[b]) { v.x = 0.f; v.y = 0.f; v.z = 0.f; v.w = 0.f; }
    short4 h, l;
    h.x = f2bf(v.x); h.y = f2bf(v.y); h.z = f2bf(v.z); h.w = f2bf(v.w);
    l.x = f2bf(v.x - bf2f(h.x)); l.y = f2bf(v.y - bf2f(h.y));
    l.z = f2bf(v.z - bf2f(h.z)); l.w = f2bf(v.w - bf2f(h.w));
    *reinterpret_cast<short4*>(xhi + (size_t)i * 4) = h;
    *reinterpret_cast<short4*>(xlo + (size_t)i * 4) = l;
}

// ---------------------------------------------------------------------------
// 5 projections. z=0 q, 1 k (single bf16 -> [bh][t][dh]); 2 v (single,
// transposed -> [bh][dh][t]); 3 eq, 4 ek (3-term split -> hi+lo [bh][t][dh]).
// ---------------------------------------------------------------------------
struct ProjP { const short* whi[5]; const short* wlo[2]; short* o[5]; short* olo[2]; };

__global__ __launch_bounds__(256) void proj_mfma(const short* __restrict__ Xh,
                                                 const short* __restrict__ Xl, ProjP p) {
    __shared__ alignas(16) short T0[4096];
    __shared__ alignas(16) short T1[4096];
    __shared__ alignas(16) short T2[4096];
    __shared__ alignas(16) short T3[4096];
    const int z = blockIdx.z;
    const short* __restrict__ Wh = p.whi[z];
    const int m0 = blockIdx.y << 7, n0 = blockIdx.x << 7;
    const int tid = threadIdx.x, lane = tid & 63, wid = tid >> 6;
    const int wm = (wid >> 1) << 6, wn = (wid & 1) << 6;
    const int kbl = lane >> 4, rl = lane & 15, rw = (lane >> 4) << 2;
    f32x4 acc[4][4] = {};
    if (z < 3) {
        for (int k0 = 0; k0 < Dn; k0 += 32) {
            stage_b<4>(Xh + (size_t)m0 * Dn + k0, Dn, T0, lane, wid);
            stage_b<4>(Wh + (size_t)n0 * Dn + k0, Dn, T1, lane, wid);
            __syncthreads();
            bf16x8 a[4], b[4];
#pragma unroll
            for (int f = 0; f < 4; ++f) {
                a[f] = fragb(T0, kbl, wm + f * 16 + rl);
                b[f] = fragb(T1, kbl, wn + f * 16 + rl);
            }
#pragma unroll
            for (int i = 0; i < 4; ++i)
#pragma unroll
                for (int j = 0; j < 4; ++j)
                    acc[i][j] = MFMA16(a[i], b[j], acc[i][j]);
            __syncthreads();
        }
    } else {
        const short* __restrict__ Wl = p.wlo[z - 3];
        for (int k0 = 0; k0 < Dn; k0 += 32) {
            stage_b<4>(Xh + (size_t)m0 * Dn + k0, Dn, T0, lane, wid);
            stage_b<4>(Xl + (size_t)m0 * Dn + k0, Dn, T1, lane, wid);
            stage_b<4>(Wh + (size_t)n0 * Dn + k0, Dn, T2, lane, wid);
            stage_b<4>(Wl + (size_t)n0 * Dn + k0, Dn, T3, lane, wid);
            __syncthreads();
            bf16x8 ah[4], al[4], bh[4], bl[4];
#pragma unroll
            for (int f = 0; f < 4; ++f) {
                ah[f] = fragb(T0, kbl, wm + f * 16 + rl);
                al[f] = fragb(T1, kbl, wm + f * 16 + rl);
                bh[f] = fragb(T2, kbl, wn + f * 16 + rl);
                bl[f] = fragb(T3, kbl, wn + f * 16 + rl);
            }
#pragma unroll
            for (int i = 0; i < 4; ++i)
#pragma unroll
                for (int j = 0; j < 4; ++j) {
                    acc[i][j] = MFMA16(al[i], bh[j], acc[i][j]);
                    acc[i][j] = MFMA16(ah[i], bl[j], acc[i][j]);
                    acc[i][j] = MFMA16(ah[i], bh[j], acc[i][j]);
                }
            __syncthreads();
        }
    }
    short* __restrict__ O = p.o[z];
    short* __restrict__ OL = (z >= 3) ? p.olo[z - 3] : nullptr;
#pragma unroll
    for (int i = 0; i < 4; ++i)
#pragma unroll
        for (int r = 0; r < 4; ++r) {
            const int m = m0 + wm + i * 16 + rw + r;
            const int b = m >> 10, t = m & 1023;
#pragma unroll
            for (int j = 0; j < 4; ++j) {
                const int n = n0 + wn + j * 16 + rl;
                const int h = n >> 7, d = n & 127;
                const float av = acc[i][j][r];
                if (z == 2) {
                    O[(((size_t)(b * Hn + h) * DH + d) << 10) + t] = f2bf(av);   // Vt
                } else {
                    const size_t idx = (((size_t)(b * Hn + h)) << 10 | t) * DH + d;
                    const short hi = f2bf(av);
                    O[idx] = hi;
                    if (z >= 3) OL[idx] = f2bf(av - bf2f(hi));
                }
            }
        }
}

// ---------------------------------------------------------------------------
// Fused: edge = eq ek^T (4-term split, ~1e-5 exact), scores = q k^T (single),
// ep = sigmoid(edge), gate via reference-structured binary-concrete,
// masked raw scores -> attn slot.
// ---------------------------------------------------------------------------
__global__ __launch_bounds__(256) void scores_edge(
    const short* __restrict__ Q, const short* __restrict__ Kb,
    const short* __restrict__ EQh, const short* __restrict__ EQl,
    const short* __restrict__ EKh, const short* __restrict__ EKl,
    const float* __restrict__ U, const int* __restrict__ lens,
    float* __restrict__ S, float* __restrict__ EP) {
    __shared__ alignas(16) short T0[4096];
    __shared__ alignas(16) short T1[4096];
    __shared__ alignas(16) short T2[4096];
    __shared__ alignas(16) short T3[4096];
    const int z = blockIdx.z;
    const int len = lens[z >> 3];
    const int m0 = blockIdx.y << 7, n0 = blockIdx.x << 7;
    const int tid = threadIdx.x, lane = tid & 63, wid = tid >> 6;
    const int wm = (wid >> 1) << 6, wn = (wid & 1) << 6;
    const int kbl = lane >> 4, rl = lane & 15, rw = (lane >> 4) << 2;
    const size_t zo = (size_t)z << 17;   // z*T*DH

    // phase A: edge, 4-term split
    f32x4 acce[4][4] = {};
    for (int k0 = 0; k0 < DH; k0 += 32) {
        stage_b<4>(EQh + zo + (size_t)m0 * DH + k0, DH, T0, lane, wid);
        stage_b<4>(EQl + zo + (size_t)m0 * DH + k0, DH, T1, lane, wid);
        stage_b<4>(EKh + zo + (size_t)n0 * DH + k0, DH, T2, lane, wid);
        stage_b<4>(EKl + zo + (size_t)n0 * DH + k0, DH, T3, lane, wid);
        __syncthreads();
        bf16x8 ah[4], al[4], bh[4], bl[4];
#pragma unroll
        for (int f = 0; f < 4; ++f) {
            ah[f] = fragb(T0, kbl, wm + f * 16 + rl);
            al[f] = fragb(T1, kbl, wm + f * 16 + rl);
            bh[f] = fragb(T2, kbl, wn + f * 16 + rl);
            bl[f] = fragb(T3, kbl, wn + f * 16 + rl);
        }
#pragma unroll
        for (int i = 0; i < 4; ++i)
#pragma unroll
            for (int j = 0; j < 4; ++j) {
                acce[i][j] = MFMA16(al[i], bl[j], acce[i][j]);
                acce[i][j] = MFMA16(al[i], bh[j], acce[i][j]);
                acce[i][j] = MFMA16(ah[i], bl[j], acce[i][j]);
                acce[i][j] = MFMA16(ah[i], bh[j], acce[i][j]);
            }
        __syncthreads();
    }

    // phase B: scores, single bf16
    f32x4 accs[4][4] = {};
    for (int k0 = 0; k0 < DH; k0 += 32) {
        stage_b<4>(Q + zo + (size_t)m0 * DH + k0, DH, T0, lane, wid);
        stage_b<4>(Kb + zo + (size_t)n0 * DH + k0, DH, T1, lane, wid);
        __syncthreads();
        bf16x8 a[4], b[4];
#pragma unroll
        for (int f = 0; f < 4; ++f) {
            a[f] = fragb(T0, kbl, wm + f * 16 + rl);
            b[f] = fragb(T1, kbl, wn + f * 16 + rl);
        }
#pragma unroll
        for (int i = 0; i < 4; ++i)
#pragma unroll
            for (int j = 0; j < 4; ++j)
                accs[i][j] = MFMA16(a[i], b[j], accs[i][j]);
        __syncthreads();
    }

    // epilogue: reference-structured gate
#pragma unroll
    for (int i = 0; i < 4; ++i)
#pragma unroll
        for (int r = 0; r < 4; ++r) {
            const int m = m0 + wm + i * 16 + rw + r;
#pragma unroll
            for (int j = 0; j < 4; ++j) {
                const int n = n0 + wn + j * 16 + rl;
                const size_t idx = ((size_t)z << 20) + ((size_t)m << 10) + n;
                const float e = acce[i][j][r];
                const float pp = 1.f / (1.f + expf(-e));
                EP[idx] = pp;
                const float u = U[idx];
                const float zz = logf(pp + EPSF) - logf(1.f - pp + EPSF) +
                                 logf(u + EPSF) - logf(1.f - u + EPSF);
                const bool valid = (zz > 0.f) && (n < len);
                S[idx] = valid ? accs[i][j][r] * (1.f / 32.f) : NEGF;
            }
        }
}

// ---------------------------------------------------------------------------
// row softmax in place; zero fully-masked rows
// ---------------------------------------------------------------------------
__global__ __launch_bounds__(256) void softmax_rows(float* __restrict__ attn) {
    __shared__ float redm[4];
    __shared__ float reds[4];
    const size_t base = (size_t)blockIdx.x * Tn;
    float4* rowp = reinterpret_cast<float4*>(attn + base);
    float4 s = rowp[threadIdx.x];
    float m = fmaxf(fmaxf(s.x, s.y), fmaxf(s.z, s.w));
#pragma unroll
    for (int off = 32; off >= 1; off >>= 1) m = fmaxf(m, __shfl_xor(m, off));
    if ((threadIdx.x & 63) == 0) redm[threadIdx.x >> 6] = m;
    __syncthreads();
    m = fmaxf(fmaxf(redm[0], redm[1]), fmaxf(redm[2], redm[3]));
    const bool any = m > -5e29f;
    float4 e;
    e.x = expf(s.x - m); e.y = expf(s.y - m);
    e.z = expf(s.z - m); e.w = expf(s.w - m);
    float sum = e.x + e.y + e.z + e.w;
#pragma unroll
    for (int off = 32; off >= 1; off >>= 1) sum += __shfl_xor(sum, off);
    if ((threadIdx.x & 63) == 0) reds[threadIdx.x >> 6] = sum;
    __syncthreads();
    sum = reds[0] + reds[1] + reds[2] + reds[3];
    const float inv = any ? 1.f / sum : 0.f;
    e.x *= inv; e.y *= inv; e.z *= inv; e.w *= inv;
    rowp[threadIdx.x] = e;
}

// ---------------------------------------------------------------------------
// ctx = relu(P @ V) per (b,h). P fp32 (attn, RNE-packed), V bf16 [dh][T].
// 512 threads (8 waves: 2m x 4n), tile 128x128(dh), K = T.
// ---------------------------------------------------------------------------
__global__ __launch_bounds__(512) void ctx_mfma(const float* __restrict__ P,
                                                const short* __restrict__ Vt,
                                                float* __restrict__ C) {
    __shared__ alignas(16) float Ps[4096];
    __shared__ alignas(16) short Vs[4096];
    const int z = blockIdx.y;
    const int bb = z >> 3, h = z & 7;
    const int m0 = blockIdx.x << 7;
    const int tid = threadIdx.x, lane = tid & 63, wid = tid >> 6;
    const int wm = (wid >> 2) << 6, wn = (wid & 3) << 5;
    const int kbl = lane >> 4, rl = lane & 15, rw = (lane >> 4) << 2;
    f32x4 acc[4][2] = {};
    for (int k0 = 0; k0 < Tn; k0 += 32) {
        stage_f<8>(P + ((size_t)z << 20) + ((size_t)m0 << 10) + k0, Tn, Ps, lane, wid);
        stage_b<8>(Vt + ((size_t)z << 17) + k0, Tn, Vs, lane, wid);
        __syncthreads();
        bf16x8 a[4], b[2];
#pragma unroll
        for (int f = 0; f < 4; ++f) a[f] = fragf(Ps, kbl, wm + f * 16 + rl);
#pragma unroll
        for (int f = 0; f < 2; ++f) b[f] = fragb(Vs, kbl, wn + f * 16 + rl);
#pragma unroll
        for (int i = 0; i < 4; ++i)
#pragma unroll
            for (int j = 0; j < 2; ++j)
                acc[i][j] = MFMA16(a[i], b[j], acc[i][j]);
        __syncthreads();
    }
#pragma unroll
    for (int i = 0; i < 4; ++i)
#pragma unroll
        for (int r = 0; r < 4; ++r) {
            const int m = m0 + wm + i * 16 + rw + r;
#pragma unroll
            for (int j = 0; j < 2; ++j) {
                const int n = wn + j * 16 + rl;
                C[(((size_t)(bb << 10 | m)) << 10) + h * DH + n] = fmaxf(acc[i][j][r], 0.f);
            }
        }
}

// ---------------------------------------------------------------------------
// h1 = LN(ctx + masked_inputs); emits fp32 + split bf16
// ---------------------------------------------------------------------------
__global__ __launch_bounds__(256) void ln1_kernel(const float* __restrict__ ctx,
                                                  const float* __restrict__ inputs,
                                                  const int* __restrict__ lengths,
                                                  const float* __restrict__ g,
                                                  const float* __restrict__ bb,
                                                  float* __restrict__ h1f,
                                                  short* __restrict__ h1hi,
                                                  short* __restrict__ h1lo) {
    __shared__ float red1[4];
    __shared__ float red2[4];
    const int row = blockIdx.x;
    const int t = row & 1023, b = row >> 10;
    const bool live = t < lengths[b];
    const size_t base = (size_t)row * Dn;
    const int tid = threadIdx.x;
    float4 v = reinterpret_cast<const float4*>(ctx + base)[tid];
    if (live) {
        const float4 r = reinterpret_cast<const float4*>(inputs + base)[tid];
        v.x += r.x; v.y += r.y; v.z += r.z; v.w += r.w;
    }
    float s = v.x + v.y + v.z + v.w;
#pragma unroll
    for (int off = 32; off >= 1; off >>= 1) s += __shfl_xor(s, off);
    if ((tid & 63) == 0) red1[tid >> 6] = s;
    __syncthreads();
    const float mu = (red1[0] + red1[1] + red1[2] + red1[3]) * (1.f / Dn);
    const float d0 = v.x - mu, d1 = v.y - mu, d2 = v.z - mu, d3 = v.w - mu;
    float sq = d0 * d0 + d1 * d1 + d2 * d2 + d3 * d3;
#pragma unroll
    for (int off = 32; off >= 1; off >>= 1) sq += __shfl_xor(sq, off);
    if ((tid & 63) == 0) red2[tid >> 6] = sq;
    __syncthreads();
    const float var = (red2[0] + red2[1] + red2[2] + red2[3]) * (1.f / Dn);
    const float rstd = rsqrtf(var + LN_EPSF);
    const float4 gv = reinterpret_cast<const float4*>(g)[tid];
    const float4 bv = reinterpret_cast<const float4*>(bb)[tid];
    float4 ov;
    ov.x = d0 * rstd * gv.x + bv.x;
    ov.y = d1 * rstd * gv.y + bv.y;
    ov.z = d2 * rstd * gv.z + bv.z;
    ov.w = d3 * rstd * gv.w + bv.w;
    reinterpret_cast<float4*>(h1f + base)[tid] = ov;
    short4 hs, ls;
    hs.x = f2bf(ov.x); hs.y = f2bf(ov.y); hs.z = f2bf(ov.z); hs.w = f2bf(ov.w);
    ls.x = f2bf(ov.x - bf2f(hs.x)); ls.y = f2bf(ov.y - bf2f(hs.y));
    ls.z = f2bf(ov.z - bf2f(hs.z)); ls.w = f2bf(ov.w - bf2f(hs.w));
    reinterpret_cast<short4*>(h1hi + base)[tid] = hs;
    reinterpret_cast<short4*>(h1lo + base)[tid] = ls;
}

// ---------------------------------------------------------------------------
// h2 = relu(h1 @ Wfc^T + bfc) + h1 ; 3-term split; 512 threads, tile 128x128
// ---------------------------------------------------------------------------
__global__ __launch_bounds__(512) void fc_mfma(const short* __restrict__ Xh,
                                               const short* __restrict__ Xl,
                                               const short* __restrict__ Wh,
                                               const short* __restrict__ Wl,
                                               const float* __restrict__ bias,
                                               const float* __restrict__ H1f,
                                               float* __restrict__ O) {
    __shared__ alignas(16) short T0[4096];
    __shared__ alignas(16) short T1[4096];
    __shared__ alignas(16) short T2[4096];
    __shared__ alignas(16) short T3[4096];
    const int m0 = blockIdx.y << 7, n0 = blockIdx.x << 7;
    const int tid = threadIdx.x, lane = tid & 63, wid = tid >> 6;
    const int wm = (wid >> 2) << 6, wn = (wid & 3) << 5;
    const int kbl = lane >> 4, rl = lane & 15, rw = (lane >> 4) << 2;
    f32x4 acc[4][2] = {};
    for (int k0 = 0; k0 < Dn; k0 += 32) {
        stage_b<8>(Xh + (size_t)m0 * Dn + k0, Dn, T0, lane, wid);
        stage_b<8>(Xl + (size_t)m0 * Dn + k0, Dn, T1, lane, wid);
        stage_b<8>(Wh + (size_t)n0 * Dn + k0, Dn, T2, lane, wid);
        stage_b<8>(Wl + (size_t)n0 * Dn + k0, Dn, T3, lane, wid);
        __syncthreads();
        bf16x8 ah[4], al[4], bh[2], bl[2];
#pragma unroll
        for (int f = 0; f < 4; ++f) {
            ah[f] = fragb(T0, kbl, wm + f * 16 + rl);
            al[f] = fragb(T1, kbl, wm + f * 16 + rl);
        }
#pragma unroll
        for (int f = 0; f < 2; ++f) {
            bh[f] = fragb(T2, kbl, wn + f * 16 + rl);
            bl[f] = fragb(T3, kbl, wn + f * 16 + rl);
        }
#pragma unroll
        for (int i = 0; i < 4; ++i)
#pragma unroll
            for (int j = 0; j < 2; ++j) {
                acc[i][j] = MFMA16(al[i], bh[j], acc[i][j]);
                acc[i][j] = MFMA16(ah[i], bl[j], acc[i][j]);
                acc[i][j] = MFMA16(ah[i], bh[j], acc[i][j]);
            }
        __syncthreads();
    }
#pragma unroll
    for (int i = 0; i < 4; ++i)
#pragma unroll
        for (int r = 0; r < 4; ++r) {
            const int m = m0 + wm + i * 16 + rw + r;
#pragma unroll
            for (int j = 0; j < 2; ++j) {
                const int n = n0 + wn + j * 16 + rl;
                const size_t idx = ((size_t)m << 10) + n;
                O[idx] = fmaxf(acc[i][j][r] + bias[n], 0.f) + H1f[idx];
            }
        }
}

// ---------------------------------------------------------------------------
// out = LN(h2), zero padded rows
// ---------------------------------------------------------------------------
__global__ __launch_bounds__(256) void ln2_kernel(const float* __restrict__ a,
                                                  const float* __restrict__ g,
                                                  const float* __restrict__ bb,
                                                  const int* __restrict__ lengths,
                                                  float* __restrict__ o) {
    __shared__ float red1[4];
    __shared__ float red2[4];
    const int row = blockIdx.x;
    const size_t base = (size_t)row * Dn;
    const int tid = threadIdx.x;
    float4 v = reinterpret_cast<const float4*>(a + base)[tid];
    float s = v.x + v.y + v.z + v.w;
#pragma unroll
    for (int off = 32; off >= 1; off >>= 1) s += __shfl_xor(s, off);
    if ((tid & 63) == 0) red1[tid >> 6] = s;
    __syncthreads();
    const float mu = (red1[0] + red1[1] + red1[2] + red1[3]) * (1.f / Dn);
    const float d0 = v.x - mu, d1 = v.y - mu, d2 = v.z - mu, d3 = v.w - mu;
    float sq = d0 * d0 + d1 * d1 + d2 * d2 + d3 * d3;
#pragma unroll
    for (int off = 32; off >= 1; off >>= 1) sq += __shfl_xor(sq, off);
    if ((tid & 63) == 0) red2[tid >> 6] = sq;
    __syncthreads();
    const float var = (red2[0] + red2[1] + red2[2] + red2[3]) * (1.f / Dn);
    const float rstd = rsqrtf(var + LN_EPSF);
    const float4 gv = reinterpret_cast<const float4*>(g)[tid];
    const float4 bv = reinterpret_cast<const float4*>(bb)[tid];
    float4 ov;
    ov.x = d0 * rstd * gv.x + bv.x;
    ov.y = d1 * rstd * gv.y + bv.y;
    ov.z = d2 * rstd * gv.z + bv.z;
    ov.w = d3 * rstd * gv.w + bv.w;
    const int t = row & 1023, b = row >> 10;
    if (t >= lengths[b]) { ov.x = 0.f; ov.y = 0.f; ov.z = 0.f; ov.w = 0.f; }
    reinterpret_cast<float4*>(o + base)[tid] = ov;
}

// ---------------------------------------------------------------------------
extern "C" void kernel_launch(void* const* d_in, const int* in_sizes, int n_in,
                              void* d_out, int out_size, void* d_ws, size_t ws_size,
                              hipStream_t stream) {
    const float* inputs = (const float*)d_in[0];
    const int* lengths = (const int*)d_in[1];
    const float* noise = (const float*)d_in[2];
    const float* bfc = (const float*)d_in[9];
    const float* ln1_g = (const float*)d_in[10];
    const float* ln1_b = (const float*)d_in[11];
    const float* ln2_g = (const float*)d_in[12];
    const float* ln2_b = (const float*)d_in[13];

    float* out = (float*)d_out;                       // (B,T,D)   4M f32
    float* attn = out + (size_t)Bn * Tn * Dn;         // (B,H,T,T) 32M f32
    float* ep = attn + (size_t)Bn * Hn * Tn * Tn;     // (B,H,T,T) 32M f32

    // workspace layout, peak 90 MB
    constexpr size_t MB = 1u << 20;
    char* W = (char*)d_ws;
    short* xhi = (short*)(W + 0 * MB);        //  8MB (dead after proj)
    short* xlo = (short*)(W + 8 * MB);        //  8MB (dead after proj)
    short* whi = (short*)(W + 16 * MB);       // 12MB hi of all 6 weights
    short* wlo = (short*)(W + 28 * MB);       //  6MB lo of Weq,Wek,Wfc
    short* qb = (short*)(W + 34 * MB);        //  8MB (dead after scores_edge)
    short* kb = (short*)(W + 42 * MB);        //  8MB (dead after scores_edge)
    short* vtb = (short*)(W + 50 * MB);       //  8MB (dead after ctx)
    short* eqh = (short*)(W + 58 * MB);       //  8MB, dead after scores_edge
    short* eql = (short*)(W + 66 * MB);       //  8MB, dead after scores_edge
    short* ekh = (short*)(W + 74 * MB);       //  8MB, dead after scores_edge
    short* ekl = (short*)(W + 82 * MB);       //  8MB, dead after scores_edge
    float* ctx = (float*)(W + 58 * MB);       // 16MB reuse eqh+eql
    float* h1f = (float*)(W + 74 * MB);       // 16MB reuse ekh+ekl
    short* h1hi = (short*)(W + 34 * MB);      //  8MB reuse qb
    short* h1lo = (short*)(W + 42 * MB);      //  8MB reuse kb
    float* h2 = (float*)(W + 0 * MB);         // 16MB reuse xhi+xlo

    // K0: weights -> bf16 hi/lo
    CvtP cp;
    for (int j = 0; j < 6; ++j) cp.src[j] = (const float*)d_in[3 + j];
    cp.hi = whi; cp.lo = wlo;
    cvt_w<<<dim3(3072), 256, 0, stream>>>(cp);

    // K1: masked x -> split bf16
    mask_x<<<dim3(4096), 256, 0, stream>>>((const float4*)inputs, lengths, xhi, xlo);

    // K2: 5 projections
    ProjP pp;
    for (int j = 0; j < 5; ++j) pp.whi[j] = whi + (size_t)j * 1048576;
    pp.wlo[0] = wlo;                 // Weq lo
    pp.wlo[1] = wlo + 1048576;       // Wek lo
    pp.o[0] = qb; pp.o[1] = kb; pp.o[2] = vtb; pp.o[3] = eqh; pp.o[4] = ekh;
    pp.olo[0] = eql; pp.olo[1] = ekl;
    proj_mfma<<<dim3(8, 32, 5), 256, 0, stream>>>(xhi, xlo, pp);

    // K3: fused edge(4-term)+scores+gate+mask -> attn slot + ep
    scores_edge<<<dim3(8, 8, 32), 256, 0, stream>>>(qb, kb, eqh, eql, ekh, ekl,
                                                    noise, lengths, attn, ep);

    // K4: softmax in place
    softmax_rows<<<dim3(Bn * Hn * Tn), 256, 0, stream>>>(attn);

    // K5: ctx = relu(attn @ v) -> (B,T,D) fp32
    ctx_mfma<<<dim3(8, 32), 512, 0, stream>>>(attn, vtb, ctx);

    // K6: h1 = LN(ctx + masked inputs) -> fp32 + split bf16
    ln1_kernel<<<dim3(Bn * Tn), 256, 0, stream>>>(ctx, inputs, lengths, ln1_g, ln1_b,
                                                  h1f, h1hi, h1lo);

    // K7: h2 = relu(h1 @ Wfc^T + bfc) + h1 (3-term split)
    fc_mfma<<<dim3(8, 32), 512, 0, stream>>>(h1hi, h1lo, whi + 5 * 1048576,
                                             wlo + 2 * 1048576, bfc, h1f, h2);

    // K8: out = LN(h2), zero padded rows
    ln2_kernel<<<dim3(Bn * Tn), 256, 0, stream>>>(h2, ln2_g, ln2_b, lengths, out);
}

// Round 5
// 516.751 us; speedup vs baseline: 3.0335x; 1.0323x over previous
//
#include <hip/hip_runtime.h>
#include <math.h>

// Shapes (fixed by the problem)
constexpr int Bn = 4, Tn = 1024, Dn = 1024, Hn = 8, DH = 128;
constexpr float EPSF = 1e-10f;
constexpr float LN_EPSF = 1e-5f;
constexpr float NEGF = -1e30f;

typedef __attribute__((ext_vector_type(8))) short bf16x8;   // 8 bf16 in 4 VGPRs
typedef __attribute__((ext_vector_type(4))) float f32x4;
typedef __attribute__((ext_vector_type(4))) unsigned uint4v;

#define MFMA16(a, b, c) __builtin_amdgcn_mfma_f32_16x16x32_bf16(a, b, c, 0, 0, 0)

// f32 -> bf16 round-to-nearest-even
__device__ __forceinline__ short f2bf(float f) {
    unsigned u = __builtin_bit_cast(unsigned, f);
    u += 0x7fffu + ((u >> 16) & 1u);
    return (short)(u >> 16);
}
__device__ __forceinline__ float bf2f(short h) {
    return __builtin_bit_cast(float, ((unsigned)(unsigned short)h) << 16);
}
__device__ __forceinline__ unsigned pack2(float a, float b) {
    return ((unsigned)(unsigned short)f2bf(a)) | (((unsigned)(unsigned short)f2bf(b)) << 16);
}

// async global->LDS, 16B per lane. lds ptr must be wave-uniform.
__device__ __forceinline__ void gload16(const void* g, void* l) {
    __builtin_amdgcn_global_load_lds((__attribute__((address_space(1))) void*)g,
                                     (__attribute__((address_space(3))) void*)l,
                                     16, 0, 0);
}

// Stage a 128x32 bf16 tile from row-major global (ld elems/row).
// LDS layout: [kb:4][r:128][8 bf16]; chunk c = kb*128 + r. 8 gload16 total.
template <int NW>
__device__ __forceinline__ void stage_b(const short* g, int ld, short* lds, int lane, int wid) {
#pragma unroll
    for (int s = 0; s < 8 / NW; ++s) {
        const int ii = wid * (8 / NW) + s;
        const int c = ii * 64 + lane;
        const int kb = c >> 7, r = c & 127;
        gload16(g + (size_t)r * ld + kb * 8, lds + ii * 512);
    }
}

// Stage a 128x32 f32 tile. LDS layout: [kb:4][half:2][r:128][4 f32]. 16 gload16.
template <int NW>
__device__ __forceinline__ void stage_f(const float* g, int ld, float* lds, int lane, int wid) {
#pragma unroll
    for (int s = 0; s < 16 / NW; ++s) {
        const int ii = wid * (16 / NW) + s;
        const int c = ii * 64 + lane;
        const int kb = c >> 8, half = (c >> 7) & 1, r = c & 127;
        gload16(g + (size_t)r * ld + kb * 8 + half * 4, lds + ii * 256);
    }
}

__device__ __forceinline__ bf16x8 fragb(const short* lds, int kbl, int r) {
    return *reinterpret_cast<const bf16x8*>(lds + kbl * 1024 + r * 8);
}

// fp32-staged fragment -> bf16x8 with RNE rounding
__device__ __forceinline__ bf16x8 fragf(const float* lds, int kbl, int r) {
    const f32x4 lo = *reinterpret_cast<const f32x4*>(lds + kbl * 1024 + r * 4);
    const f32x4 hi = *reinterpret_cast<const f32x4*>(lds + kbl * 1024 + 512 + r * 4);
    uint4v p;
    p[0] = pack2(lo[0], lo[1]);
    p[1] = pack2(lo[2], lo[3]);
    p[2] = pack2(hi[0], hi[1]);
    p[3] = pack2(hi[2], hi[3]);
    return __builtin_bit_cast(bf16x8, p);
}

// ---------------------------------------------------------------------------
// weights -> bf16 hi (all 6) + lo (Weq,Wek,Wfc only: mats 3,4,5)
// ---------------------------------------------------------------------------
struct CvtP { const float* src[6]; short* hi; short* lo; };

__global__ __launch_bounds__(256) void cvt_w(CvtP p) {
    const int i = blockIdx.x * 256 + threadIdx.x;       // 786432 threads x 8 elems
    const int mat = i >> 17;
    const int off = (i & 131071) * 8;
    const float* s = p.src[mat] + off;
    const float4 a = *reinterpret_cast<const float4*>(s);
    const float4 b = *reinterpret_cast<const float4*>(s + 4);
    const float va[8] = {a.x, a.y, a.z, a.w, b.x, b.y, b.z, b.w};
    bf16x8 h, l;
#pragma unroll
    for (int j = 0; j < 8; ++j) {
        h[j] = f2bf(va[j]);
        l[j] = f2bf(va[j] - bf2f(h[j]));
    }
    *reinterpret_cast<bf16x8*>(p.hi + (size_t)mat * 1048576 + off) = h;
    if (mat >= 3)
        *reinterpret_cast<bf16x8*>(p.lo + (size_t)(mat - 3) * 1048576 + off) = l;
}

// ---------------------------------------------------------------------------
// x = where(pad,0,inputs) -> split bf16 (hi, lo)
// ---------------------------------------------------------------------------
__global__ __launch_bounds__(256) void mask_x(const float4* __restrict__ in,
                                              const int* __restrict__ lengths,
                                              short* __restrict__ xhi,
                                              short* __restrict__ xlo) {
    const int i = blockIdx.x * 256 + threadIdx.x;       // 1M float4
    const int row = i >> 8;
    const int t = row & 1023, b = row >> 10;
    float4 v = in[i];
    if (t >= lengths[b]) { v.x = 0.f; v.y = 0.f; v.z = 0.f; v.w = 0.f; }
    short4 h, l;
    h.x = f2bf(v.x); h.y = f2bf(v.y); h.z = f2bf(v.z); h.w = f2bf(v.w);
    l.x = f2bf(v.x - bf2f(h.x)); l.y = f2bf(v.y - bf2f(h.y));
    l.z = f2bf(v.z - bf2f(h.z)); l.w = f2bf(v.w - bf2f(h.w));
    *reinterpret_cast<short4*>(xhi + (size_t)i * 4) = h;
    *reinterpret_cast<short4*>(xlo + (size_t)i * 4) = l;
}

// ---------------------------------------------------------------------------
// 5 projections. z=0 q, 1 k (single bf16 -> [bh][t][dh]); 2 v (single,
// transposed -> [bh][dh][t]); 3 eq, 4 ek (3-term split -> hi+lo [bh][t][dh]).
// ---------------------------------------------------------------------------
struct ProjP { const short* whi[5]; const short* wlo[2]; short* o[5]; short* olo[2]; };

__global__ __launch_bounds__(256) void proj_mfma(const short* __restrict__ Xh,
                                                 const short* __restrict__ Xl, ProjP p) {
    __shared__ alignas(16) short T0[4096];
    __shared__ alignas(16) short T1[4096];
    __shared__ alignas(16) short T2[4096];
    __shared__ alignas(16) short T3[4096];
    const int z = blockIdx.z;
    const short* __restrict__ Wh = p.whi[z];
    const int m0 = blockIdx.y << 7, n0 = blockIdx.x << 7;
    const int tid = threadIdx.x, lane = tid & 63, wid = tid >> 6;
    const int wm = (wid >> 1) << 6, wn = (wid & 1) << 6;
    const int kbl = lane >> 4, rl = lane & 15, rw = (lane >> 4) << 2;
    f32x4 acc[4][4] = {};
    if (z < 3) {
        for (int k0 = 0; k0 < Dn; k0 += 32) {
            stage_b<4>(Xh + (size_t)m0 * Dn + k0, Dn, T0, lane, wid);
            stage_b<4>(Wh + (size_t)n0 * Dn + k0, Dn, T1, lane, wid);
            __syncthreads();
            bf16x8 a[4], b[4];
#pragma unroll
            for (int f = 0; f < 4; ++f) {
                a[f] = fragb(T0, kbl, wm + f * 16 + rl);
                b[f] = fragb(T1, kbl, wn + f * 16 + rl);
            }
#pragma unroll
            for (int i = 0; i < 4; ++i)
#pragma unroll
                for (int j = 0; j < 4; ++j)
                    acc[i][j] = MFMA16(a[i], b[j], acc[i][j]);
            __syncthreads();
        }
    } else {
        const short* __restrict__ Wl = p.wlo[z - 3];
        for (int k0 = 0; k0 < Dn; k0 += 32) {
            stage_b<4>(Xh + (size_t)m0 * Dn + k0, Dn, T0, lane, wid);
            stage_b<4>(Xl + (size_t)m0 * Dn + k0, Dn, T1, lane, wid);
            stage_b<4>(Wh + (size_t)n0 * Dn + k0, Dn, T2, lane, wid);
            stage_b<4>(Wl + (size_t)n0 * Dn + k0, Dn, T3, lane, wid);
            __syncthreads();
            bf16x8 ah[4], al[4], bh[4], bl[4];
#pragma unroll
            for (int f = 0; f < 4; ++f) {
                ah[f] = fragb(T0, kbl, wm + f * 16 + rl);
                al[f] = fragb(T1, kbl, wm + f * 16 + rl);
                bh[f] = fragb(T2, kbl, wn + f * 16 + rl);
                bl[f] = fragb(T3, kbl, wn + f * 16 + rl);
            }
#pragma unroll
            for (int i = 0; i < 4; ++i)
#pragma unroll
                for (int j = 0; j < 4; ++j) {
                    acc[i][j] = MFMA16(al[i], bh[j], acc[i][j]);
                    acc[i][j] = MFMA16(ah[i], bl[j], acc[i][j]);
                    acc[i][j] = MFMA16(ah[i], bh[j], acc[i][j]);
                }
            __syncthreads();
        }
    }
    short* __restrict__ O = p.o[z];
    short* __restrict__ OL = (z >= 3) ? p.olo[z - 3] : nullptr;
#pragma unroll
    for (int i = 0; i < 4; ++i)
#pragma unroll
        for (int r = 0; r < 4; ++r) {
            const int m = m0 + wm + i * 16 + rw + r;
            const int b = m >> 10, t = m & 1023;
#pragma unroll
            for (int j = 0; j < 4; ++j) {
                const int n = n0 + wn + j * 16 + rl;
                const int h = n >> 7, d = n & 127;
                const float av = acc[i][j][r];
                if (z == 2) {
                    O[(((size_t)(b * Hn + h) * DH + d) << 10) + t] = f2bf(av);   // Vt
                } else {
                    const size_t idx = (((size_t)(b * Hn + h)) << 10 | t) * DH + d;
                    const short hi = f2bf(av);
                    O[idx] = hi;
                    if (z >= 3) OL[idx] = f2bf(av - bf2f(hi));
                }
            }
        }
}

// ---------------------------------------------------------------------------
// Fused: edge = eq ek^T (4-term split, ~1e-5 exact), scores = q k^T (single),
// ep = sigmoid(edge), gate via binary-concrete using the eps-exact identity
// logit(sigmoid(e)) == e, masked raw scores -> attn slot.
// ---------------------------------------------------------------------------
__global__ __launch_bounds__(256) void scores_edge(
    const short* __restrict__ Q, const short* __restrict__ Kb,
    const short* __restrict__ EQh, const short* __restrict__ EQl,
    const short* __restrict__ EKh, const short* __restrict__ EKl,
    const float* __restrict__ U, const int* __restrict__ lens,
    float* __restrict__ S, float* __restrict__ EP) {
    __shared__ alignas(16) short T0[4096];
    __shared__ alignas(16) short T1[4096];
    __shared__ alignas(16) short T2[4096];
    __shared__ alignas(16) short T3[4096];
    const int z = blockIdx.z;
    const int len = lens[z >> 3];
    const int m0 = blockIdx.y << 7, n0 = blockIdx.x << 7;
    const int tid = threadIdx.x, lane = tid & 63, wid = tid >> 6;
    const int wm = (wid >> 1) << 6, wn = (wid & 1) << 6;
    const int kbl = lane >> 4, rl = lane & 15, rw = (lane >> 4) << 2;
    const size_t zo = (size_t)z << 17;   // z*T*DH

    // phase A: edge, 4-term split
    f32x4 acce[4][4] = {};
    for (int k0 = 0; k0 < DH; k0 += 32) {
        stage_b<4>(EQh + zo + (size_t)m0 * DH + k0, DH, T0, lane, wid);
        stage_b<4>(EQl + zo + (size_t)m0 * DH + k0, DH, T1, lane, wid);
        stage_b<4>(EKh + zo + (size_t)n0 * DH + k0, DH, T2, lane, wid);
        stage_b<4>(EKl + zo + (size_t)n0 * DH + k0, DH, T3, lane, wid);
        __syncthreads();
        bf16x8 ah[4], al[4], bh[4], bl[4];
#pragma unroll
        for (int f = 0; f < 4; ++f) {
            ah[f] = fragb(T0, kbl, wm + f * 16 + rl);
            al[f] = fragb(T1, kbl, wm + f * 16 + rl);
            bh[f] = fragb(T2, kbl, wn + f * 16 + rl);
            bl[f] = fragb(T3, kbl, wn + f * 16 + rl);
        }
#pragma unroll
        for (int i = 0; i < 4; ++i)
#pragma unroll
            for (int j = 0; j < 4; ++j) {
                acce[i][j] = MFMA16(al[i], bl[j], acce[i][j]);
                acce[i][j] = MFMA16(al[i], bh[j], acce[i][j]);
                acce[i][j] = MFMA16(ah[i], bl[j], acce[i][j]);
                acce[i][j] = MFMA16(ah[i], bh[j], acce[i][j]);
            }
        __syncthreads();
    }

    // phase B: scores, single bf16
    f32x4 accs[4][4] = {};
    for (int k0 = 0; k0 < DH; k0 += 32) {
        stage_b<4>(Q + zo + (size_t)m0 * DH + k0, DH, T0, lane, wid);
        stage_b<4>(Kb + zo + (size_t)n0 * DH + k0, DH, T1, lane, wid);
        __syncthreads();
        bf16x8 a[4], b[4];
#pragma unroll
        for (int f = 0; f < 4; ++f) {
            a[f] = fragb(T0, kbl, wm + f * 16 + rl);
            b[f] = fragb(T1, kbl, wn + f * 16 + rl);
        }
#pragma unroll
        for (int i = 0; i < 4; ++i)
#pragma unroll
            for (int j = 0; j < 4; ++j)
                accs[i][j] = MFMA16(a[i], b[j], accs[i][j]);
        __syncthreads();
    }

    // epilogue: fast-math gate (identity: logit(sigmoid(e)) == e)
#pragma unroll
    for (int i = 0; i < 4; ++i)
#pragma unroll
        for (int r = 0; r < 4; ++r) {
            const int m = m0 + wm + i * 16 + rw + r;
#pragma unroll
            for (int j = 0; j < 4; ++j) {
                const int n = n0 + wn + j * 16 + rl;
                const size_t idx = ((size_t)z << 20) + ((size_t)m << 10) + n;
                const float e = acce[i][j][r];
                EP[idx] = 1.f / (1.f + __expf(-e));
                const float u = U[idx];
                const float zz = e + __logf(u + EPSF) - __logf(1.f - u + EPSF);
                const bool valid = (zz > 0.f) && (n < len);
                S[idx] = valid ? accs[i][j][r] * (1.f / 32.f) : NEGF;
            }
        }
}

// ---------------------------------------------------------------------------
// Fused softmax + ctx. Each block owns rows [m0,m0+128) of one (b,h):
//  phase 1   : online per-row max/sum of raw masked scores (4 threads/row)
//  phase 1.5 : in-place normalize P = exp(s-m)/sum in the attn slot
//  phase 2   : ctx = relu(P @ V), P staged fp32 -> RNE bf16 fragments
// ---------------------------------------------------------------------------
__global__ __launch_bounds__(512) void softmax_ctx(float* __restrict__ P,
                                                   const short* __restrict__ Vt,
                                                   float* __restrict__ C) {
    __shared__ alignas(16) float Ps[4096];
    __shared__ alignas(16) short Vs[4096];
    const int z = blockIdx.y;
    const int bb = z >> 3, h = z & 7;
    const int m0 = blockIdx.x << 7;
    const int tid = threadIdx.x, lane = tid & 63, wid = tid >> 6;

    {
        const int r = tid >> 2, qd = tid & 3;
        float* rowp = P + ((size_t)z << 20) + ((size_t)(m0 + r) << 10) + qd * 8;
        float mrun = -3.0e38f, lrun = 0.f;
#pragma unroll 8
        for (int c = 0; c < 32; ++c) {
            const float4 v0 = *reinterpret_cast<const float4*>(rowp + c * 32);
            const float4 v1 = *reinterpret_cast<const float4*>(rowp + c * 32 + 4);
            const float cm = fmaxf(fmaxf(fmaxf(v0.x, v0.y), fmaxf(v0.z, v0.w)),
                                   fmaxf(fmaxf(v1.x, v1.y), fmaxf(v1.z, v1.w)));
            const float mn = fmaxf(mrun, cm);
            lrun = lrun * __expf(mrun - mn) +
                   __expf(v0.x - mn) + __expf(v0.y - mn) +
                   __expf(v0.z - mn) + __expf(v0.w - mn) +
                   __expf(v1.x - mn) + __expf(v1.y - mn) +
                   __expf(v1.z - mn) + __expf(v1.w - mn);
            mrun = mn;
        }
#pragma unroll
        for (int off = 1; off <= 2; off <<= 1) {
            const float mo = __shfl_xor(mrun, off);
            const float lo2 = __shfl_xor(lrun, off);
            const float mn = fmaxf(mrun, mo);
            lrun = lrun * __expf(mrun - mn) + lo2 * __expf(mo - mn);
            mrun = mn;
        }
        const float inv = (mrun > -5e29f) ? 1.f / lrun : 0.f;
#pragma unroll 8
        for (int c = 0; c < 32; ++c) {
            float4 v0 = *reinterpret_cast<const float4*>(rowp + c * 32);
            float4 v1 = *reinterpret_cast<const float4*>(rowp + c * 32 + 4);
            v0.x = __expf(v0.x - mrun) * inv; v0.y = __expf(v0.y - mrun) * inv;
            v0.z = __expf(v0.z - mrun) * inv; v0.w = __expf(v0.w - mrun) * inv;
            v1.x = __expf(v1.x - mrun) * inv; v1.y = __expf(v1.y - mrun) * inv;
            v1.z = __expf(v1.z - mrun) * inv; v1.w = __expf(v1.w - mrun) * inv;
            *reinterpret_cast<float4*>(rowp + c * 32) = v0;
            *reinterpret_cast<float4*>(rowp + c * 32 + 4) = v1;
        }
    }
    __syncthreads();

    // phase 2: GEMM (old ctx_mfma body)
    const int wm = (wid >> 2) << 6, wn = (wid & 3) << 5;
    const int kbl = lane >> 4, rl = lane & 15, rw = (lane >> 4) << 2;
    f32x4 acc[4][2] = {};
    for (int k0 = 0; k0 < Tn; k0 += 32) {
        stage_f<8>(P + ((size_t)z << 20) + ((size_t)m0 << 10) + k0, Tn, Ps, lane, wid);
        stage_b<8>(Vt + ((size_t)z << 17) + k0, Tn, Vs, lane, wid);
        __syncthreads();
        bf16x8 a[4], b[2];
#pragma unroll
        for (int f = 0; f < 4; ++f) a[f] = fragf(Ps, kbl, wm + f * 16 + rl);
#pragma unroll
        for (int f = 0; f < 2; ++f) b[f] = fragb(Vs, kbl, wn + f * 16 + rl);
#pragma unroll
        for (int i = 0; i < 4; ++i)
#pragma unroll
            for (int j = 0; j < 2; ++j)
                acc[i][j] = MFMA16(a[i], b[j], acc[i][j]);
        __syncthreads();
    }
#pragma unroll
    for (int i = 0; i < 4; ++i)
#pragma unroll
        for (int r = 0; r < 4; ++r) {
            const int m = m0 + wm + i * 16 + rw + r;
#pragma unroll
            for (int j = 0; j < 2; ++j) {
                const int n = wn + j * 16 + rl;
                C[(((size_t)(bb << 10 | m)) << 10) + h * DH + n] = fmaxf(acc[i][j][r], 0.f);
            }
        }
}

// ---------------------------------------------------------------------------
// h1 = LN(ctx + masked_inputs); emits fp32 + split bf16
// ---------------------------------------------------------------------------
__global__ __launch_bounds__(256) void ln1_kernel(const float* __restrict__ ctx,
                                                  const float* __restrict__ inputs,
                                                  const int* __restrict__ lengths,
                                                  const float* __restrict__ g,
                                                  const float* __restrict__ bb,
                                                  float* __restrict__ h1f,
                                                  short* __restrict__ h1hi,
                                                  short* __restrict__ h1lo) {
    __shared__ float red1[4];
    __shared__ float red2[4];
    const int row = blockIdx.x;
    const int t = row & 1023, b = row >> 10;
    const bool live = t < lengths[b];
    const size_t base = (size_t)row * Dn;
    const int tid = threadIdx.x;
    float4 v = reinterpret_cast<const float4*>(ctx + base)[tid];
    if (live) {
        const float4 r = reinterpret_cast<const float4*>(inputs + base)[tid];
        v.x += r.x; v.y += r.y; v.z += r.z; v.w += r.w;
    }
    float s = v.x + v.y + v.z + v.w;
#pragma unroll
    for (int off = 32; off >= 1; off >>= 1) s += __shfl_xor(s, off);
    if ((tid & 63) == 0) red1[tid >> 6] = s;
    __syncthreads();
    const float mu = (red1[0] + red1[1] + red1[2] + red1[3]) * (1.f / Dn);
    const float d0 = v.x - mu, d1 = v.y - mu, d2 = v.z - mu, d3 = v.w - mu;
    float sq = d0 * d0 + d1 * d1 + d2 * d2 + d3 * d3;
#pragma unroll
    for (int off = 32; off >= 1; off >>= 1) sq += __shfl_xor(sq, off);
    if ((tid & 63) == 0) red2[tid >> 6] = sq;
    __syncthreads();
    const float var = (red2[0] + red2[1] + red2[2] + red2[3]) * (1.f / Dn);
    const float rstd = rsqrtf(var + LN_EPSF);
    const float4 gv = reinterpret_cast<const float4*>(g)[tid];
    const float4 bv = reinterpret_cast<const float4*>(bb)[tid];
    float4 ov;
    ov.x = d0 * rstd * gv.x + bv.x;
    ov.y = d1 * rstd * gv.y + bv.y;
    ov.z = d2 * rstd * gv.z + bv.z;
    ov.w = d3 * rstd * gv.w + bv.w;
    reinterpret_cast<float4*>(h1f + base)[tid] = ov;
    short4 hs, ls;
    hs.x = f2bf(ov.x); hs.y = f2bf(ov.y); hs.z = f2bf(ov.z); hs.w = f2bf(ov.w);
    ls.x = f2bf(ov.x - bf2f(hs.x)); ls.y = f2bf(ov.y - bf2f(hs.y));
    ls.z = f2bf(ov.z - bf2f(hs.z)); ls.w = f2bf(ov.w - bf2f(hs.w));
    reinterpret_cast<short4*>(h1hi + base)[tid] = hs;
    reinterpret_cast<short4*>(h1lo + base)[tid] = ls;
}

// ---------------------------------------------------------------------------
// h2 = relu(h1 @ Wfc^T + bfc) + h1 ; 3-term split; 512 threads, tile 128x128
// ---------------------------------------------------------------------------
__global__ __launch_bounds__(512) void fc_mfma(const short* __restrict__ Xh,
                                               const short* __restrict__ Xl,
                                               const short* __restrict__ Wh,
                                               const short* __restrict__ Wl,
                                               const float* __restrict__ bias,
                                               const float* __restrict__ H1f,
                                               float* __restrict__ O) {
    __shared__ alignas(16) short T0[4096];
    __shared__ alignas(16) short T1[4096];
    __shared__ alignas(16) short T2[4096];
    __shared__ alignas(16) short T3[4096];
    const int m0 = blockIdx.y << 7, n0 = blockIdx.x << 7;
    const int tid = threadIdx.x, lane = tid & 63, wid = tid >> 6;
    const int wm = (wid >> 2) << 6, wn = (wid & 3) << 5;
    const int kbl = lane >> 4, rl = lane & 15, rw = (lane >> 4) << 2;
    f32x4 acc[4][2] = {};
    for (int k0 = 0; k0 < Dn; k0 += 32) {
        stage_b<8>(Xh + (size_t)m0 * Dn + k0, Dn, T0, lane, wid);
        stage_b<8>(Xl + (size_t)m0 * Dn + k0, Dn, T1, lane, wid);
        stage_b<8>(Wh + (size_t)n0 * Dn + k0, Dn, T2, lane, wid);
        stage_b<8>(Wl + (size_t)n0 * Dn + k0, Dn, T3, lane, wid);
        __syncthreads();
        bf16x8 ah[4], al[4], bh[2], bl[2];
#pragma unroll
        for (int f = 0; f < 4; ++f) {
            ah[f] = fragb(T0, kbl, wm + f * 16 + rl);
            al[f] = fragb(T1, kbl, wm + f * 16 + rl);
        }
#pragma unroll
        for (int f = 0; f < 2; ++f) {
            bh[f] = fragb(T2, kbl, wn + f * 16 + rl);
            bl[f] = fragb(T3, kbl, wn + f * 16 + rl);
        }
#pragma unroll
        for (int i = 0; i < 4; ++i)
#pragma unroll
            for (int j = 0; j < 2; ++j) {
                acc[i][j] = MFMA16(al[i], bh[j], acc[i][j]);
                acc[i][j] = MFMA16(ah[i], bl[j], acc[i][j]);
                acc[i][j] = MFMA16(ah[i], bh[j], acc[i][j]);
            }
        __syncthreads();
    }
#pragma unroll
    for (int i = 0; i < 4; ++i)
#pragma unroll
        for (int r = 0; r < 4; ++r) {
            const int m = m0 + wm + i * 16 + rw + r;
#pragma unroll
            for (int j = 0; j < 2; ++j) {
                const int n = n0 + wn + j * 16 + rl;
                const size_t idx = ((size_t)m << 10) + n;
                O[idx] = fmaxf(acc[i][j][r] + bias[n], 0.f) + H1f[idx];
            }
        }
}

// ---------------------------------------------------------------------------
// out = LN(h2), zero padded rows
// ---------------------------------------------------------------------------
__global__ __launch_bounds__(256) void ln2_kernel(const float* __restrict__ a,
                                                  const float* __restrict__ g,
                                                  const float* __restrict__ bb,
                                                  const int* __restrict__ lengths,
                                                  float* __restrict__ o) {
    __shared__ float red1[4];
    __shared__ float red2[4];
    const int row = blockIdx.x;
    const size_t base = (size_t)row * Dn;
    const int tid = threadIdx.x;
    float4 v = reinterpret_cast<const float4*>(a + base)[tid];
    float s = v.x + v.y + v.z + v.w;
#pragma unroll
    for (int off = 32; off >= 1; off >>= 1) s += __shfl_xor(s, off);
    if ((tid & 63) == 0) red1[tid >> 6] = s;
    __syncthreads();
    const float mu = (red1[0] + red1[1] + red1[2] + red1[3]) * (1.f / Dn);
    const float d0 = v.x - mu, d1 = v.y - mu, d2 = v.z - mu, d3 = v.w - mu;
    float sq = d0 * d0 + d1 * d1 + d2 * d2 + d3 * d3;
#pragma unroll
    for (int off = 32; off >= 1; off >>= 1) sq += __shfl_xor(sq, off);
    if ((tid & 63) == 0) red2[tid >> 6] = sq;
    __syncthreads();
    const float var = (red2[0] + red2[1] + red2[2] + red2[3]) * (1.f / Dn);
    const float rstd = rsqrtf(var + LN_EPSF);
    const float4 gv = reinterpret_cast<const float4*>(g)[tid];
    const float4 bv = reinterpret_cast<const float4*>(bb)[tid];
    float4 ov;
    ov.x = d0 * rstd * gv.x + bv.x;
    ov.y = d1 * rstd * gv.y + bv.y;
    ov.z = d2 * rstd * gv.z + bv.z;
    ov.w = d3 * rstd * gv.w + bv.w;
    const int t = row & 1023, b = row >> 10;
    if (t >= lengths[b]) { ov.x = 0.f; ov.y = 0.f; ov.z = 0.f; ov.w = 0.f; }
    reinterpret_cast<float4*>(o + base)[tid] = ov;
}

// ---------------------------------------------------------------------------
extern "C" void kernel_launch(void* const* d_in, const int* in_sizes, int n_in,
                              void* d_out, int out_size, void* d_ws, size_t ws_size,
                              hipStream_t stream) {
    const float* inputs = (const float*)d_in[0];
    const int* lengths = (const int*)d_in[1];
    const float* noise = (const float*)d_in[2];
    const float* bfc = (const float*)d_in[9];
    const float* ln1_g = (const float*)d_in[10];
    const float* ln1_b = (const float*)d_in[11];
    const float* ln2_g = (const float*)d_in[12];
    const float* ln2_b = (const float*)d_in[13];

    float* out = (float*)d_out;                       // (B,T,D)   4M f32
    float* attn = out + (size_t)Bn * Tn * Dn;         // (B,H,T,T) 32M f32
    float* ep = attn + (size_t)Bn * Hn * Tn * Tn;     // (B,H,T,T) 32M f32

    // workspace layout, peak 90 MB
    constexpr size_t MB = 1u << 20;
    char* W = (char*)d_ws;
    short* xhi = (short*)(W + 0 * MB);        //  8MB (dead after proj)
    short* xlo = (short*)(W + 8 * MB);        //  8MB (dead after proj)
    short* whi = (short*)(W + 16 * MB);       // 12MB hi of all 6 weights
    short* wlo = (short*)(W + 28 * MB);       //  6MB lo of Weq,Wek,Wfc
    short* qb = (short*)(W + 34 * MB);        //  8MB (dead after scores_edge)
    short* kb = (short*)(W + 42 * MB);        //  8MB (dead after scores_edge)
    short* vtb = (short*)(W + 50 * MB);       //  8MB (dead after softmax_ctx)
    short* eqh = (short*)(W + 58 * MB);       //  8MB, dead after scores_edge
    short* eql = (short*)(W + 66 * MB);       //  8MB, dead after scores_edge
    short* ekh = (short*)(W + 74 * MB);       //  8MB, dead after scores_edge
    short* ekl = (short*)(W + 82 * MB);       //  8MB, dead after scores_edge
    float* ctx = (float*)(W + 58 * MB);       // 16MB reuse eqh+eql
    float* h1f = (float*)(W + 74 * MB);       // 16MB reuse ekh+ekl
    short* h1hi = (short*)(W + 34 * MB);      //  8MB reuse qb
    short* h1lo = (short*)(W + 42 * MB);      //  8MB reuse kb
    float* h2 = (float*)(W + 0 * MB);         // 16MB reuse xhi+xlo

    // K0: weights -> bf16 hi/lo
    CvtP cp;
    for (int j = 0; j < 6; ++j) cp.src[j] = (const float*)d_in[3 + j];
    cp.hi = whi; cp.lo = wlo;
    cvt_w<<<dim3(3072), 256, 0, stream>>>(cp);

    // K1: masked x -> split bf16
    mask_x<<<dim3(4096), 256, 0, stream>>>((const float4*)inputs, lengths, xhi, xlo);

    // K2: 5 projections
    ProjP pp;
    for (int j = 0; j < 5; ++j) pp.whi[j] = whi + (size_t)j * 1048576;
    pp.wlo[0] = wlo;                 // Weq lo
    pp.wlo[1] = wlo + 1048576;       // Wek lo
    pp.o[0] = qb; pp.o[1] = kb; pp.o[2] = vtb; pp.o[3] = eqh; pp.o[4] = ekh;
    pp.olo[0] = eql; pp.olo[1] = ekl;
    proj_mfma<<<dim3(8, 32, 5), 256, 0, stream>>>(xhi, xlo, pp);

    // K3: fused edge(4-term)+scores+gate+mask -> attn slot + ep
    scores_edge<<<dim3(8, 8, 32), 256, 0, stream>>>(qb, kb, eqh, eql, ekh, ekl,
                                                    noise, lengths, attn, ep);

    // K4: fused softmax (in place) + ctx = relu(attn @ v) -> (B,T,D) fp32
    softmax_ctx<<<dim3(8, 32), 512, 0, stream>>>(attn, vtb, ctx);

    // K5: h1 = LN(ctx + masked inputs) -> fp32 + split bf16
    ln1_kernel<<<dim3(Bn * Tn), 256, 0, stream>>>(ctx, inputs, lengths, ln1_g, ln1_b,
                                                  h1f, h1hi, h1lo);

    // K6: h2 = relu(h1 @ Wfc^T + bfc) + h1 (3-term split)
    fc_mfma<<<dim3(8, 32), 512, 0, stream>>>(h1hi, h1lo, whi + 5 * 1048576,
                                             wlo + 2 * 1048576, bfc, h1f, h2);

    // K7: out = LN(h2), zero padded rows
    ln2_kernel<<<dim3(Bn * Tn), 256, 0, stream>>>(h2, ln2_g, ln2_b, lengths, out);
}